// Round 13
// baseline (120.431 us; speedup 1.0000x reference)
//
#include <hip/hip_runtime.h>
#include <hip/hip_fp16.h>
#include <math.h>

// Problem constants
#define NB 392      // n = b*oh*ow = 2*14*14
#define NI 288      // K*K*B = 9*32
#define NC 32       // C
#define NQ 16       // PSIZE
#define CQ 512      // NC*NQ
#define CH 544      // B*(PSIZE+1)
#define EPSV 1e-6f

// votes are fp8 e4m3 scaled by 32; routing descales algebraically.
#define VSCALE 32.0f
#define VINV (1.0f / 32.0f)

// out layout (floats)
#define OFF_AOUT 200704       // NB*CQ
#define OFF_CAT  213248       // OFF_AOUT + NB*NC

#define RT_THREADS 512
#define RT_WAVES 8

typedef _Float16 v4h __attribute__((ext_vector_type(4)));
typedef float v4f __attribute__((ext_vector_type(4)));
typedef float v2f __attribute__((ext_vector_type(2)));

// ---------------------------------------------------------------------------
// Gather from x via the unfold channel-major reinterpret.
__device__ __forceinline__ float gather_x(const float* __restrict__ x, int n, int j) {
    int c_idx = j / 9;
    int rem = j - c_idx * 9;
    int ki = rem / 3;
    int kj = rem - ki * 3;
    int b_ = n / 196;
    int rest = n - b_ * 196;
    int yy = rest / 14;
    int xx = rest - yy * 14;
    int iy = yy + ki - 1;
    int ix = xx + kj - 1;
    float v = 0.f;
    if ((unsigned)iy < 14u && (unsigned)ix < 14u)
        v = x[((b_ * 14 + iy) * 14 + ix) * CH + c_idx];
    return v;
}

// ---------------------------------------------------------------------------
// FULLY-FUSED votes: reads x and wts directly (prep_k eliminated).
// Block (mtt 0..6, i 0..287), 256 threads = 4 waves, M=64 rows of n.
// - wts[i] (32 KB fp32) is read coalesced (float4) and transposed in-flight
//   into LDS w16l[cq][16k] fp16 (16 KB) -- B-frags are then the same
//   contiguous 8 B ds_read_b64 as the precomputed-w16 version.
// - A-frags (4 halves/lane) gathered from x in-lane; block (mtt,i) owns its
//   n-range exclusively, so total gather work == old prep_k's (no dup).
// - Output fp8 e4m3 scaled x32, staged via byte tile [64][144], stored as
//   64 rows x 128 B contiguous per ct-chunk.
// LDS = 16 KB + 9 KB = 25.3 KB -> 6 blocks/CU.
__global__ __launch_bounds__(256) void votes_k(const float* __restrict__ x,
                                               const float* __restrict__ wts,
                                               uchar* __restrict__ votes) {
    __shared__ ushort w16l[8192];       // 16 KB: [cq][16k] fp16
    __shared__ uchar tile[64 * 144];    // 9 KB
    int mtt = blockIdx.x;         // 0..6
    int i = blockIdx.y;           // 0..287
    int t = threadIdx.x;
    int wv = t >> 6;
    int l = t & 63;
    int col = l & 15;
    int quad = l >> 4;

    // stage + transpose wts[i]: coalesced float4 reads, scattered u16 LDS
    // writes (8-way, one-time). w16l[(c*16+q)*16 + p] = (half)wts[i][c][p][q]
    {
        const float4* src = (const float4*)(wts + (size_t)i * 8192);
#pragma unroll
        for (int it = 0; it < 8; ++it) {
            float4 f4 = src[it * 256 + t];
            int fidx = (it * 256 + t) * 4;
            int c = fidx >> 8;
            int p = (fidx >> 4) & 15;
            int q0 = fidx & 15;          // q0, q0+1, q0+2, q0+3
            ushort* wb = &w16l[(c * 16 + q0) * 16 + p];
            wb[0]  = __half_as_ushort(__float2half(f4.x));
            wb[16] = __half_as_ushort(__float2half(f4.y));
            wb[32] = __half_as_ushort(__float2half(f4.z));
            wb[48] = __half_as_ushort(__float2half(f4.w));
        }
    }

    // A-frag: gather 4 p-values from x in-lane (overlaps the LDS staging)
    int n_row = mtt * 64 + wv * 16 + col;
    v4h av = {};
    if (n_row < NB) {
        int jb = (i >> 5) * CH + (i & 31) * 16 + quad * 4;
#pragma unroll
        for (int kk = 0; kk < 4; ++kk)
            av[kk] = (_Float16)gather_x(x, n_row, jb + kk);
    }
    __syncthreads();

    for (int ch = 0; ch < 4; ++ch) {
#pragma unroll
        for (int c8 = 0; c8 < 8; ++c8) {
            int ct = ch * 8 + c8;
            v4h bv = *(const v4h*)&w16l[(ct * 16 + col) * 16 + quad * 4];
            v4f acc = {0.f, 0.f, 0.f, 0.f};
            acc = __builtin_amdgcn_mfma_f32_16x16x16f16(av, bv, acc, 0, 0, 0);
            uint u01 = __builtin_amdgcn_cvt_pk_fp8_f32(acc[0] * VSCALE, acc[1] * VSCALE, 0, false);
            uint u23 = __builtin_amdgcn_cvt_pk_fp8_f32(acc[2] * VSCALE, acc[3] * VSCALE, 0, false);
            uchar* tb = &tile[(wv * 16 + quad * 4) * 144 + c8 * 16 + col];
            tb[0 * 144] = (uchar)(u01 & 0xFF);
            tb[1 * 144] = (uchar)((u01 >> 8) & 0xFF);
            tb[2 * 144] = (uchar)(u23 & 0xFF);
            tb[3 * 144] = (uchar)((u23 >> 8) & 0xFF);
        }
        __syncthreads();
        // 64 rows x 8 uint4 = 512 uint4; 2 steps; 8 lanes store a row's 128 B.
#pragma unroll
        for (int k = 0; k < 2; ++k) {
            int idx = k * 256 + t;
            int row = idx >> 3;
            int off = idx & 7;
            int n_out = mtt * 64 + row;
            if (n_out < NB) {
                uint4 d = *(const uint4*)&tile[row * 144 + off * 16];
                *(uint4*)(votes + (((size_t)n_out * NI + i) << 9) + ch * 128 + off * 16) = d;
            }
        }
        __syncthreads();
    }
}

// ---------------------------------------------------------------------------
// Fused dynamic routing, 3 passes over fp8 votes. Block = n, 512 threads.
// Computes its own afs (288 trivial gathers) -- no afac array / prep needed.
// Lane: c = l&31, g = l>>5; wave wv step s handles i = (s*8+wv)*2+g.
// vjr pre-scaled x1/32 so the agreement dot uses raw fp8-decoded votes;
// s_j descaled once per column per iter. Scratch [q*32+c] conflict-free.
__global__ __launch_bounds__(RT_THREADS) void routing_k(const uchar* __restrict__ votes,
                                                        const float* __restrict__ x,
                                                        float* __restrict__ out) {
    __shared__ float afs[NI];
    __shared__ float sred[RT_WAVES * CQ];   // 16 KB, [group][q*32+c]
    __shared__ float vj[CQ];                // [q*32+c]
    __shared__ float aout_s[NC];

    int n = blockIdx.x;
    int t = threadIdx.x;
    int wv = t >> 6;      // 0..7
    int l = t & 63;
    int c = l & 31;
    int g = l >> 5;

    if (t < NI) {
        int j = (t >> 5) * CH + 512 + (t & 31);
        float v = gather_x(x, n, j);
        float a = fminf(fmaxf(v, 1e-4f), 1.0f);
        afs[t] = a / (a + EPSV);
    }
    __syncthreads();

    const uchar* vb = votes + (size_t)n * NI * 512;
    float vjr[16];    // cumulative vj, PRE-SCALED by 1/32
    float sreg[16];

#define VROW(S) (((const uint4*)(vb + ((size_t)(((((S) << 3) + wv) << 1) + g) << 9)))[c])

    for (int iter = 0; iter < 3; ++iter) {
#pragma unroll
        for (int q = 0; q < 16; ++q) sreg[q] = 0.f;

        uint4 f0 = VROW(0), f1 = VROW(1), f2 = VROW(2);

#pragma clang loop unroll_count(2)
        for (int s = 0; s < 18; ++s) {
            int i = ((s << 3) + wv) * 2 + g;
            uint4 cur = f0;
            f0 = f1; f1 = f2;
            if (s + 3 < 18) f2 = VROW(s + 3);

            float vt[16];   // raw fp8-decoded (x32-scaled votes)
            {
                v2f p;
                p = __builtin_amdgcn_cvt_pk_f32_fp8(cur.x, false); vt[0] = p[0];  vt[1] = p[1];
                p = __builtin_amdgcn_cvt_pk_f32_fp8(cur.x, true);  vt[2] = p[0];  vt[3] = p[1];
                p = __builtin_amdgcn_cvt_pk_f32_fp8(cur.y, false); vt[4] = p[0];  vt[5] = p[1];
                p = __builtin_amdgcn_cvt_pk_f32_fp8(cur.y, true);  vt[6] = p[0];  vt[7] = p[1];
                p = __builtin_amdgcn_cvt_pk_f32_fp8(cur.z, false); vt[8] = p[0];  vt[9] = p[1];
                p = __builtin_amdgcn_cvt_pk_f32_fp8(cur.z, true);  vt[10] = p[0]; vt[11] = p[1];
                p = __builtin_amdgcn_cvt_pk_f32_fp8(cur.w, false); vt[12] = p[0]; vt[13] = p[1];
                p = __builtin_amdgcn_cvt_pk_f32_fp8(cur.w, true);  vt[14] = p[0]; vt[15] = p[1];
            }
            float cij;
            if (iter == 0) {
                cij = afs[i] * (1.0f / 32.0f);
            } else {
                float ah = 0.f;   // vt(raw) . vjr(pre-scaled) == true dot
#pragma unroll
                for (int q = 0; q < 16; ++q) ah += vt[q] * vjr[q];
                float e = __expf(ah);
                float ssum = e;
                ssum += __shfl_xor(ssum, 1);
                ssum += __shfl_xor(ssum, 2);
                ssum += __shfl_xor(ssum, 4);
                ssum += __shfl_xor(ssum, 8);
                ssum += __shfl_xor(ssum, 16);
                cij = e * __builtin_amdgcn_rcpf(ssum) * afs[i];
            }
#pragma unroll
            for (int q = 0; q < 16; ++q) sreg[q] += cij * vt[q];
        }

        // fold g-halves, write 8 partial groups (layout [q*32+c]: bank==c)
#pragma unroll
        for (int q = 0; q < 16; ++q) sreg[q] += __shfl_xor(sreg[q], 32);
        if (g == 0) {
            float* sw = &sred[wv * CQ + c];
#pragma unroll
            for (int q = 0; q < 16; ++q) sw[q * 32] = sreg[q];
        }
        __syncthreads();
        {
            float ssum = 0.f;   // 512 threads == CQ columns
#pragma unroll
            for (int k = 0; k < RT_WAVES; ++k) ssum += sred[k * CQ + t];
            sred[t] = ssum * VINV;   // descale the x32 fp8 encoding ONCE
        }
        __syncthreads();

        // squash (threads 0..31, one c each; element (c,q) at sred[q*32+c])
        if (t < NC) {
            float s2 = 0.f;
#pragma unroll
            for (int q = 0; q < 16; ++q) {
                float s = sred[q * 32 + t];
                s2 += s * s;
            }
            float f = (s2 / (1.f + s2)) / sqrtf(s2 + EPSV);
            float vn2 = 0.f;
#pragma unroll
            for (int q = 0; q < 16; ++q) {
                float v = f * sred[q * 32 + t];
                vj[q * 32 + t] = v;
                vn2 += v * v;
            }
            if (iter == 2) {
                float ao = sqrtf(vn2 + EPSV);
                ao = fminf(fmaxf(ao, 1e-4f), 1.f - 1e-4f);
                aout_s[t] = ao;
            }
        }
        __syncthreads();
        if (iter < 2) {
#pragma unroll
            for (int q = 0; q < 16; ++q) {
                float v = vj[q * 32 + c] * VINV;   // pre-scale for the raw dot
                vjr[q] = (iter == 0) ? v : vjr[q] + v;
            }
        }
    }

    // outputs: p_out, a_out, concat(out).  canonical idx t: c=t>>4, q=t&15
    {
        float v = vj[(t & 15) * 32 + (t >> 4)];
        out[(size_t)n * CQ + t] = v;
        out[OFF_CAT + (size_t)n * 544 + t] = v;
    }
    if (t < NC) {
        float ao = aout_s[t];
        out[OFF_AOUT + n * 32 + t] = ao;
        out[OFF_CAT + (size_t)n * 544 + 512 + t] = ao;
    }
}

// ---------------------------------------------------------------------------
extern "C" void kernel_launch(void* const* d_in, const int* in_sizes, int n_in,
                              void* d_out, int out_size, void* d_ws, size_t ws_size,
                              hipStream_t stream) {
    const float* x = (const float*)d_in[0];
    const float* wts = (const float*)d_in[1];
    float* out = (float*)d_out;
    uchar* votes = (uchar*)d_ws;   // NB*NI*512 bytes fp8

    hipLaunchKernelGGL(votes_k, dim3(7, NI), dim3(256), 0, stream,
                       x, wts, votes);
    hipLaunchKernelGGL(routing_k, dim3(NB), dim3(RT_THREADS), 0, stream,
                       votes, x, out);
}

// Round 14
// 116.864 us; speedup vs baseline: 1.0305x; 1.0305x over previous
//
#include <hip/hip_runtime.h>
#include <hip/hip_fp16.h>
#include <math.h>

// Problem constants
#define NB 392      // n = b*oh*ow = 2*14*14
#define NI 288      // K*K*B = 9*32
#define NC 32       // C
#define NQ 16       // PSIZE
#define CQ 512      // NC*NQ
#define CH 544      // B*(PSIZE+1)
#define EPSV 1e-6f

// votes are fp8 e4m3 scaled by 32; routing descales algebraically.
#define VSCALE 32.0f
#define VINV (1.0f / 32.0f)

// ws layout (bytes): votes fp8 first, then w16 fp16
#define VOT_BYTES ((size_t)NB * NI * 512)       // 57,802,752
// w16: NI*CQ*16 halves = 4,718,592 halves

// out layout (floats)
#define OFF_AOUT 200704       // NB*CQ
#define OFF_CAT  213248       // OFF_AOUT + NB*NC

#define RT_THREADS 512
#define RT_WAVES 8

typedef _Float16 v4h __attribute__((ext_vector_type(4)));
typedef float v4f __attribute__((ext_vector_type(4)));
typedef float v2f __attribute__((ext_vector_type(2)));

// ---------------------------------------------------------------------------
// Gather from x via the unfold channel-major reinterpret.
__device__ __forceinline__ float gather_x(const float* __restrict__ x, int n, int j) {
    int c_idx = j / 9;
    int rem = j - c_idx * 9;
    int ki = rem / 3;
    int kj = rem - ki * 3;
    int b_ = n / 196;
    int rest = n - b_ * 196;
    int yy = rest / 14;
    int xx = rest - yy * 14;
    int iy = yy + ki - 1;
    int ix = xx + kj - 1;
    float v = 0.f;
    if ((unsigned)iy < 14u && (unsigned)ix < 14u)
        v = x[((b_ * 14 + iy) * 14 + ix) * CH + c_idx];
    return v;
}

// ---------------------------------------------------------------------------
// w16[i][cq][16k] = (half)wts[i][cq>>4][k][cq&15], via LDS transpose.
// Block (i, half-cq): coalesced float4 reads, coalesced uint4 writes.
// (Validated structure from rounds 11-12; in-block transpose in votes_k was
// the round-13 regression: 8-way-conflict LDS scatter + wts re-read x7.)
__global__ __launch_bounds__(256) void prep_w(const float* __restrict__ wts,
                                              ushort* __restrict__ w16) {
    __shared__ float wl[4096];   // 16 KB
    int i = blockIdx.x >> 1;
    int h = blockIdx.x & 1;
    int t = threadIdx.x;
    const float4* src = (const float4*)(wts + (size_t)i * 8192 + h * 4096);
#pragma unroll
    for (int it = 0; it < 4; ++it)
        *(float4*)&wl[(it * 256 + t) * 4] = src[it * 256 + t];
    __syncthreads();
    uint4* dst = (uint4*)(w16 + (size_t)i * 8192 + h * 4096);  // 512 uint4
#pragma unroll
    for (int it = 0; it < 2; ++it) {
        int idx = it * 256 + t;          // (cl, m): m covers k = 8m..8m+7
        int cl = idx >> 1;
        int m = idx & 1;
        int base = (cl >> 4) * 256 + (cl & 15);
        uint v[4];
#pragma unroll
        for (int kk = 0; kk < 4; ++kk) {
            __half2 hh = __floats2half2_rn(wl[base + (8 * m + 2 * kk) * 16],
                                           wl[base + (8 * m + 2 * kk + 1) * 16]);
            v[kk] = *(uint*)&hh;
        }
        dst[cl * 2 + m] = make_uint4(v[0], v[1], v[2], v[3]);
    }
}

// ---------------------------------------------------------------------------
// votes via mfma 16x16x16 f16 (K=16 exact), fp8 e4m3 output scaled x32.
// Block (mtt 0..6, i 0..287), 256 threads = 4 waves, M=64 rows of n.
// - A-frags (4 halves/lane) gathered from x in-lane (round-13's good half:
//   block owns its n-range exclusively -> same total work as a prep pass,
//   but no global round-trip).
// - B-frags read from pre-transposed global w16: the wave's 64 lanes cover
//   one dense 512 B segment per ct (col*32 + quad*8 byte offsets) -> fully
//   coalesced, L2-served across mtt re-reads.
// - ct-chunked fp8 staging via byte tile [64][144] (9 KB -> 8 blocks/CU),
//   64 rows x 128 B contiguous stores per chunk.
__global__ __launch_bounds__(256) void votes_k(const float* __restrict__ x,
                                               const ushort* __restrict__ w16,
                                               uchar* __restrict__ votes) {
    __shared__ uchar tile[64 * 144];    // 9 KB
    int mtt = blockIdx.x;         // 0..6
    int i = blockIdx.y;           // 0..287
    int t = threadIdx.x;
    int wv = t >> 6;
    int l = t & 63;
    int col = l & 15;
    int quad = l >> 4;

    // A-frag: gather 4 p-values from x in-lane
    int n_row = mtt * 64 + wv * 16 + col;
    v4h av = {};
    if (n_row < NB) {
        int jb = (i >> 5) * CH + (i & 31) * 16 + quad * 4;
#pragma unroll
        for (int kk = 0; kk < 4; ++kk)
            av[kk] = (_Float16)gather_x(x, n_row, jb + kk);
    }

    const ushort* wbase = w16 + (size_t)i * 8192;

    for (int ch = 0; ch < 4; ++ch) {
#pragma unroll
        for (int c8 = 0; c8 < 8; ++c8) {
            int ct = ch * 8 + c8;
            v4h bv = *(const v4h*)(wbase + (ct * 16 + col) * 16 + quad * 4);
            v4f acc = {0.f, 0.f, 0.f, 0.f};
            acc = __builtin_amdgcn_mfma_f32_16x16x16f16(av, bv, acc, 0, 0, 0);
            uint u01 = __builtin_amdgcn_cvt_pk_fp8_f32(acc[0] * VSCALE, acc[1] * VSCALE, 0, false);
            uint u23 = __builtin_amdgcn_cvt_pk_fp8_f32(acc[2] * VSCALE, acc[3] * VSCALE, 0, false);
            uchar* tb = &tile[(wv * 16 + quad * 4) * 144 + c8 * 16 + col];
            tb[0 * 144] = (uchar)(u01 & 0xFF);
            tb[1 * 144] = (uchar)((u01 >> 8) & 0xFF);
            tb[2 * 144] = (uchar)(u23 & 0xFF);
            tb[3 * 144] = (uchar)((u23 >> 8) & 0xFF);
        }
        __syncthreads();
        // 64 rows x 8 uint4 = 512 uint4; 2 steps; 8 lanes store a row's 128 B.
#pragma unroll
        for (int k = 0; k < 2; ++k) {
            int idx = k * 256 + t;
            int row = idx >> 3;
            int off = idx & 7;
            int n_out = mtt * 64 + row;
            if (n_out < NB) {
                uint4 d = *(const uint4*)&tile[row * 144 + off * 16];
                *(uint4*)(votes + (((size_t)n_out * NI + i) << 9) + ch * 128 + off * 16) = d;
            }
        }
        __syncthreads();
    }
}

// ---------------------------------------------------------------------------
// Fused dynamic routing, 3 passes over fp8 votes. Block = n, 512 threads.
// Computes its own afs (288 trivial gathers). Lane: c = l&31, g = l>>5;
// wave wv step s handles i = (s*8+wv)*2+g. vjr pre-scaled x1/32 so the
// agreement dot uses raw fp8-decoded votes; s_j descaled once per column per
// iter. Scratch [q*32+c] conflict-free.
__global__ __launch_bounds__(RT_THREADS) void routing_k(const uchar* __restrict__ votes,
                                                        const float* __restrict__ x,
                                                        float* __restrict__ out) {
    __shared__ float afs[NI];
    __shared__ float sred[RT_WAVES * CQ];   // 16 KB, [group][q*32+c]
    __shared__ float vj[CQ];                // [q*32+c]
    __shared__ float aout_s[NC];

    int n = blockIdx.x;
    int t = threadIdx.x;
    int wv = t >> 6;      // 0..7
    int l = t & 63;
    int c = l & 31;
    int g = l >> 5;

    if (t < NI) {
        int j = (t >> 5) * CH + 512 + (t & 31);
        float v = gather_x(x, n, j);
        float a = fminf(fmaxf(v, 1e-4f), 1.0f);
        afs[t] = a / (a + EPSV);
    }
    __syncthreads();

    const uchar* vb = votes + (size_t)n * NI * 512;
    float vjr[16];    // cumulative vj, PRE-SCALED by 1/32
    float sreg[16];

#define VROW(S) (((const uint4*)(vb + ((size_t)(((((S) << 3) + wv) << 1) + g) << 9)))[c])

    for (int iter = 0; iter < 3; ++iter) {
#pragma unroll
        for (int q = 0; q < 16; ++q) sreg[q] = 0.f;

        uint4 f0 = VROW(0), f1 = VROW(1), f2 = VROW(2);

#pragma clang loop unroll_count(2)
        for (int s = 0; s < 18; ++s) {
            int i = ((s << 3) + wv) * 2 + g;
            uint4 cur = f0;
            f0 = f1; f1 = f2;
            if (s + 3 < 18) f2 = VROW(s + 3);

            float vt[16];   // raw fp8-decoded (x32-scaled votes)
            {
                v2f p;
                p = __builtin_amdgcn_cvt_pk_f32_fp8(cur.x, false); vt[0] = p[0];  vt[1] = p[1];
                p = __builtin_amdgcn_cvt_pk_f32_fp8(cur.x, true);  vt[2] = p[0];  vt[3] = p[1];
                p = __builtin_amdgcn_cvt_pk_f32_fp8(cur.y, false); vt[4] = p[0];  vt[5] = p[1];
                p = __builtin_amdgcn_cvt_pk_f32_fp8(cur.y, true);  vt[6] = p[0];  vt[7] = p[1];
                p = __builtin_amdgcn_cvt_pk_f32_fp8(cur.z, false); vt[8] = p[0];  vt[9] = p[1];
                p = __builtin_amdgcn_cvt_pk_f32_fp8(cur.z, true);  vt[10] = p[0]; vt[11] = p[1];
                p = __builtin_amdgcn_cvt_pk_f32_fp8(cur.w, false); vt[12] = p[0]; vt[13] = p[1];
                p = __builtin_amdgcn_cvt_pk_f32_fp8(cur.w, true);  vt[14] = p[0]; vt[15] = p[1];
            }
            float cij;
            if (iter == 0) {
                cij = afs[i] * (1.0f / 32.0f);
            } else {
                float ah = 0.f;   // vt(raw) . vjr(pre-scaled) == true dot
#pragma unroll
                for (int q = 0; q < 16; ++q) ah += vt[q] * vjr[q];
                float e = __expf(ah);
                float ssum = e;
                ssum += __shfl_xor(ssum, 1);
                ssum += __shfl_xor(ssum, 2);
                ssum += __shfl_xor(ssum, 4);
                ssum += __shfl_xor(ssum, 8);
                ssum += __shfl_xor(ssum, 16);
                cij = e * __builtin_amdgcn_rcpf(ssum) * afs[i];
            }
#pragma unroll
            for (int q = 0; q < 16; ++q) sreg[q] += cij * vt[q];
        }

        // fold g-halves, write 8 partial groups (layout [q*32+c]: bank==c)
#pragma unroll
        for (int q = 0; q < 16; ++q) sreg[q] += __shfl_xor(sreg[q], 32);
        if (g == 0) {
            float* sw = &sred[wv * CQ + c];
#pragma unroll
            for (int q = 0; q < 16; ++q) sw[q * 32] = sreg[q];
        }
        __syncthreads();
        {
            float ssum = 0.f;   // 512 threads == CQ columns
#pragma unroll
            for (int k = 0; k < RT_WAVES; ++k) ssum += sred[k * CQ + t];
            sred[t] = ssum * VINV;   // descale the x32 fp8 encoding ONCE
        }
        __syncthreads();

        // squash (threads 0..31, one c each; element (c,q) at sred[q*32+c])
        if (t < NC) {
            float s2 = 0.f;
#pragma unroll
            for (int q = 0; q < 16; ++q) {
                float s = sred[q * 32 + t];
                s2 += s * s;
            }
            float f = (s2 / (1.f + s2)) / sqrtf(s2 + EPSV);
            float vn2 = 0.f;
#pragma unroll
            for (int q = 0; q < 16; ++q) {
                float v = f * sred[q * 32 + t];
                vj[q * 32 + t] = v;
                vn2 += v * v;
            }
            if (iter == 2) {
                float ao = sqrtf(vn2 + EPSV);
                ao = fminf(fmaxf(ao, 1e-4f), 1.f - 1e-4f);
                aout_s[t] = ao;
            }
        }
        __syncthreads();
        if (iter < 2) {
#pragma unroll
            for (int q = 0; q < 16; ++q) {
                float v = vj[q * 32 + c] * VINV;   // pre-scale for the raw dot
                vjr[q] = (iter == 0) ? v : vjr[q] + v;
            }
        }
    }

    // outputs: p_out, a_out, concat(out).  canonical idx t: c=t>>4, q=t&15
    {
        float v = vj[(t & 15) * 32 + (t >> 4)];
        out[(size_t)n * CQ + t] = v;
        out[OFF_CAT + (size_t)n * 544 + t] = v;
    }
    if (t < NC) {
        float ao = aout_s[t];
        out[OFF_AOUT + n * 32 + t] = ao;
        out[OFF_CAT + (size_t)n * 544 + 512 + t] = ao;
    }
}

// ---------------------------------------------------------------------------
extern "C" void kernel_launch(void* const* d_in, const int* in_sizes, int n_in,
                              void* d_out, int out_size, void* d_ws, size_t ws_size,
                              hipStream_t stream) {
    const float* x = (const float*)d_in[0];
    const float* wts = (const float*)d_in[1];
    float* out = (float*)d_out;
    uchar* votes = (uchar*)d_ws;                      // 57.8 MB fp8
    ushort* w16 = (ushort*)((uchar*)d_ws + VOT_BYTES); // 9.4 MB fp16

    hipLaunchKernelGGL(prep_w, dim3(NI * 2), dim3(256), 0, stream, wts, w16);
    hipLaunchKernelGGL(votes_k, dim3(7, NI), dim3(256), 0, stream,
                       x, w16, votes);
    hipLaunchKernelGGL(routing_k, dim3(NB), dim3(RT_THREADS), 0, stream,
                       votes, x, out);
}

// Round 15
// 116.801 us; speedup vs baseline: 1.0311x; 1.0005x over previous
//
#include <hip/hip_runtime.h>
#include <hip/hip_fp16.h>
#include <math.h>

// Problem constants
#define NB 392      // n = b*oh*ow = 2*14*14
#define NI 288      // K*K*B = 9*32
#define NC 32       // C
#define NQ 16       // PSIZE
#define CQ 512      // NC*NQ
#define CH 544      // B*(PSIZE+1)
#define EPSV 1e-6f

// votes are fp8 e4m3 scaled by 32; routing descales algebraically.
#define VSCALE 32.0f
#define VINV (1.0f / 32.0f)

// ws layout (bytes): votes fp8 first, then w16 fp16
#define VOT_BYTES ((size_t)NB * NI * 512)       // 57,802,752

// out layout (floats)
#define OFF_AOUT 200704       // NB*CQ
#define OFF_CAT  213248       // OFF_AOUT + NB*NC

#define RT_THREADS 512
#define RT_WAVES 8

typedef _Float16 v4h __attribute__((ext_vector_type(4)));
typedef float v4f __attribute__((ext_vector_type(4)));
typedef float v2f __attribute__((ext_vector_type(2)));

// ---------------------------------------------------------------------------
// Gather from x via the unfold channel-major reinterpret.
__device__ __forceinline__ float gather_x(const float* __restrict__ x, int n, int j) {
    int c_idx = j / 9;
    int rem = j - c_idx * 9;
    int ki = rem / 3;
    int kj = rem - ki * 3;
    int b_ = n / 196;
    int rest = n - b_ * 196;
    int yy = rest / 14;
    int xx = rest - yy * 14;
    int iy = yy + ki - 1;
    int ix = xx + kj - 1;
    float v = 0.f;
    if ((unsigned)iy < 14u && (unsigned)ix < 14u)
        v = x[((b_ * 14 + iy) * 14 + ix) * CH + c_idx];
    return v;
}

// ---------------------------------------------------------------------------
// w16[i][cq][16k] = (half)wts[i][cq>>4][k][cq&15], via LDS transpose.
__global__ __launch_bounds__(256) void prep_w(const float* __restrict__ wts,
                                              ushort* __restrict__ w16) {
    __shared__ float wl[4096];   // 16 KB
    int i = blockIdx.x >> 1;
    int h = blockIdx.x & 1;
    int t = threadIdx.x;
    const float4* src = (const float4*)(wts + (size_t)i * 8192 + h * 4096);
#pragma unroll
    for (int it = 0; it < 4; ++it)
        *(float4*)&wl[(it * 256 + t) * 4] = src[it * 256 + t];
    __syncthreads();
    uint4* dst = (uint4*)(w16 + (size_t)i * 8192 + h * 4096);  // 512 uint4
#pragma unroll
    for (int it = 0; it < 2; ++it) {
        int idx = it * 256 + t;          // (cl, m): m covers k = 8m..8m+7
        int cl = idx >> 1;
        int m = idx & 1;
        int base = (cl >> 4) * 256 + (cl & 15);
        uint v[4];
#pragma unroll
        for (int kk = 0; kk < 4; ++kk) {
            __half2 hh = __floats2half2_rn(wl[base + (8 * m + 2 * kk) * 16],
                                           wl[base + (8 * m + 2 * kk + 1) * 16]);
            v[kk] = *(uint*)&hh;
        }
        dst[cl * 2 + m] = make_uint4(v[0], v[1], v[2], v[3]);
    }
}

// ---------------------------------------------------------------------------
// votes via mfma 16x16x16 f16 with SWAPPED operands: mfma(bv, av) computes
// D[cq][n] so lane (col,quad) holds 4 CONSECUTIVE cq (quad*4+r) for ONE
// n-row (col). cvt_pk_fp8_f32 packs them into a single u32 (low/high halves)
// with zero extra ops, and the LDS stage is ONE ds_write_b32 at dword
// offset (wv*16+col)*36 + c8*4 + quad -> bank (4col+quad)%32 = exact 2-way
// (free), replacing round-14's 4 scattered ds_write_b8 (4-way + same-dword
// byte hazards). Same 9 KB tile (pitch 144 B), same 128 B-row store phase.
__global__ __launch_bounds__(256) void votes_k(const float* __restrict__ x,
                                               const ushort* __restrict__ w16,
                                               uchar* __restrict__ votes) {
    __shared__ uint tile[64 * 36];      // 9 KB, pitch 36 dwords (144 B)
    int mtt = blockIdx.x;         // 0..6
    int i = blockIdx.y;           // 0..287
    int t = threadIdx.x;
    int wv = t >> 6;
    int l = t & 63;
    int col = l & 15;
    int quad = l >> 4;

    // A-side p-frag: gather 4 p-values from x in-lane (n_row = col-mapped)
    int n_row = mtt * 64 + wv * 16 + col;
    v4h av = {};
    if (n_row < NB) {
        int jb = (i >> 5) * CH + (i & 31) * 16 + quad * 4;
#pragma unroll
        for (int kk = 0; kk < 4; ++kk)
            av[kk] = (_Float16)gather_x(x, n_row, jb + kk);
    }

    const ushort* wbase = w16 + (size_t)i * 8192;
    const uchar* tileb = (const uchar*)tile;

    for (int ch = 0; ch < 4; ++ch) {
#pragma unroll
        for (int c8 = 0; c8 < 8; ++c8) {
            int ct = ch * 8 + c8;
            v4h bv = *(const v4h*)(wbase + (ct * 16 + col) * 16 + quad * 4);
            v4f acc = {0.f, 0.f, 0.f, 0.f};
            acc = __builtin_amdgcn_mfma_f32_16x16x16f16(bv, av, acc, 0, 0, 0);
            // lane holds votes[n=...+col][cq = ct*16 + quad*4 + 0..3]
            uint u = __builtin_amdgcn_cvt_pk_fp8_f32(acc[0] * VSCALE, acc[1] * VSCALE, 0, false);
            u = __builtin_amdgcn_cvt_pk_fp8_f32(acc[2] * VSCALE, acc[3] * VSCALE, u, true);
            tile[(wv * 16 + col) * 36 + c8 * 4 + quad] = u;
        }
        __syncthreads();
        // 64 rows x 8 uint4 = 512 uint4; 2 steps; 8 lanes store a row's 128 B.
#pragma unroll
        for (int k = 0; k < 2; ++k) {
            int idx = k * 256 + t;
            int row = idx >> 3;
            int off = idx & 7;
            int n_out = mtt * 64 + row;
            if (n_out < NB) {
                uint4 d = *(const uint4*)&tileb[row * 144 + off * 16];
                *(uint4*)(votes + (((size_t)n_out * NI + i) << 9) + ch * 128 + off * 16) = d;
            }
        }
        __syncthreads();
    }
}

// ---------------------------------------------------------------------------
// Fused dynamic routing, 3 passes over fp8 votes. Block = n, 512 threads.
// Computes its own afs (288 trivial gathers). Lane: c = l&31, g = l>>5;
// wave wv step s handles i = (s*8+wv)*2+g. vjr pre-scaled x1/32 so the
// agreement dot uses raw fp8-decoded votes; s_j descaled once per column per
// iter. Scratch [q*32+c] conflict-free. Depth-4 prefetch for MLP on the
// HBM-bound first pass (~80 VGPR, still 12 waves/CU at 392x8-wave grid).
__global__ __launch_bounds__(RT_THREADS) void routing_k(const uchar* __restrict__ votes,
                                                        const float* __restrict__ x,
                                                        float* __restrict__ out) {
    __shared__ float afs[NI];
    __shared__ float sred[RT_WAVES * CQ];   // 16 KB, [group][q*32+c]
    __shared__ float vj[CQ];                // [q*32+c]
    __shared__ float aout_s[NC];

    int n = blockIdx.x;
    int t = threadIdx.x;
    int wv = t >> 6;      // 0..7
    int l = t & 63;
    int c = l & 31;
    int g = l >> 5;

    if (t < NI) {
        int j = (t >> 5) * CH + 512 + (t & 31);
        float v = gather_x(x, n, j);
        float a = fminf(fmaxf(v, 1e-4f), 1.0f);
        afs[t] = a / (a + EPSV);
    }
    __syncthreads();

    const uchar* vb = votes + (size_t)n * NI * 512;
    float vjr[16];    // cumulative vj, PRE-SCALED by 1/32
    float sreg[16];

#define VROW(S) (((const uint4*)(vb + ((size_t)(((((S) << 3) + wv) << 1) + g) << 9)))[c])

    for (int iter = 0; iter < 3; ++iter) {
#pragma unroll
        for (int q = 0; q < 16; ++q) sreg[q] = 0.f;

        uint4 f0 = VROW(0), f1 = VROW(1), f2 = VROW(2), f3 = VROW(3);

#pragma clang loop unroll_count(2)
        for (int s = 0; s < 18; ++s) {
            int i = ((s << 3) + wv) * 2 + g;
            uint4 cur = f0;
            f0 = f1; f1 = f2; f2 = f3;
            if (s + 4 < 18) f3 = VROW(s + 4);

            float vt[16];   // raw fp8-decoded (x32-scaled votes)
            {
                v2f p;
                p = __builtin_amdgcn_cvt_pk_f32_fp8(cur.x, false); vt[0] = p[0];  vt[1] = p[1];
                p = __builtin_amdgcn_cvt_pk_f32_fp8(cur.x, true);  vt[2] = p[0];  vt[3] = p[1];
                p = __builtin_amdgcn_cvt_pk_f32_fp8(cur.y, false); vt[4] = p[0];  vt[5] = p[1];
                p = __builtin_amdgcn_cvt_pk_f32_fp8(cur.y, true);  vt[6] = p[0];  vt[7] = p[1];
                p = __builtin_amdgcn_cvt_pk_f32_fp8(cur.z, false); vt[8] = p[0];  vt[9] = p[1];
                p = __builtin_amdgcn_cvt_pk_f32_fp8(cur.z, true);  vt[10] = p[0]; vt[11] = p[1];
                p = __builtin_amdgcn_cvt_pk_f32_fp8(cur.w, false); vt[12] = p[0]; vt[13] = p[1];
                p = __builtin_amdgcn_cvt_pk_f32_fp8(cur.w, true);  vt[14] = p[0]; vt[15] = p[1];
            }
            float cij;
            if (iter == 0) {
                cij = afs[i] * (1.0f / 32.0f);
            } else {
                float ah = 0.f;   // vt(raw) . vjr(pre-scaled) == true dot
#pragma unroll
                for (int q = 0; q < 16; ++q) ah += vt[q] * vjr[q];
                float e = __expf(ah);
                float ssum = e;
                ssum += __shfl_xor(ssum, 1);
                ssum += __shfl_xor(ssum, 2);
                ssum += __shfl_xor(ssum, 4);
                ssum += __shfl_xor(ssum, 8);
                ssum += __shfl_xor(ssum, 16);
                cij = e * __builtin_amdgcn_rcpf(ssum) * afs[i];
            }
#pragma unroll
            for (int q = 0; q < 16; ++q) sreg[q] += cij * vt[q];
        }

        // fold g-halves, write 8 partial groups (layout [q*32+c]: bank==c)
#pragma unroll
        for (int q = 0; q < 16; ++q) sreg[q] += __shfl_xor(sreg[q], 32);
        if (g == 0) {
            float* sw = &sred[wv * CQ + c];
#pragma unroll
            for (int q = 0; q < 16; ++q) sw[q * 32] = sreg[q];
        }
        __syncthreads();
        {
            float ssum = 0.f;   // 512 threads == CQ columns
#pragma unroll
            for (int k = 0; k < RT_WAVES; ++k) ssum += sred[k * CQ + t];
            sred[t] = ssum * VINV;   // descale the x32 fp8 encoding ONCE
        }
        __syncthreads();

        // squash (threads 0..31, one c each; element (c,q) at sred[q*32+c])
        if (t < NC) {
            float s2 = 0.f;
#pragma unroll
            for (int q = 0; q < 16; ++q) {
                float s = sred[q * 32 + t];
                s2 += s * s;
            }
            float f = (s2 / (1.f + s2)) / sqrtf(s2 + EPSV);
            float vn2 = 0.f;
#pragma unroll
            for (int q = 0; q < 16; ++q) {
                float v = f * sred[q * 32 + t];
                vj[q * 32 + t] = v;
                vn2 += v * v;
            }
            if (iter == 2) {
                float ao = sqrtf(vn2 + EPSV);
                ao = fminf(fmaxf(ao, 1e-4f), 1.f - 1e-4f);
                aout_s[t] = ao;
            }
        }
        __syncthreads();
        if (iter < 2) {
#pragma unroll
            for (int q = 0; q < 16; ++q) {
                float v = vj[q * 32 + c] * VINV;   // pre-scale for the raw dot
                vjr[q] = (iter == 0) ? v : vjr[q] + v;
            }
        }
    }

    // outputs: p_out, a_out, concat(out).  canonical idx t: c=t>>4, q=t&15
    {
        float v = vj[(t & 15) * 32 + (t >> 4)];
        out[(size_t)n * CQ + t] = v;
        out[OFF_CAT + (size_t)n * 544 + t] = v;
    }
    if (t < NC) {
        float ao = aout_s[t];
        out[OFF_AOUT + n * 32 + t] = ao;
        out[OFF_CAT + (size_t)n * 544 + 512 + t] = ao;
    }
}

// ---------------------------------------------------------------------------
extern "C" void kernel_launch(void* const* d_in, const int* in_sizes, int n_in,
                              void* d_out, int out_size, void* d_ws, size_t ws_size,
                              hipStream_t stream) {
    const float* x = (const float*)d_in[0];
    const float* wts = (const float*)d_in[1];
    float* out = (float*)d_out;
    uchar* votes = (uchar*)d_ws;                      // 57.8 MB fp8
    ushort* w16 = (ushort*)((uchar*)d_ws + VOT_BYTES); // 9.4 MB fp16

    hipLaunchKernelGGL(prep_w, dim3(NI * 2), dim3(256), 0, stream, wts, w16);
    hipLaunchKernelGGL(votes_k, dim3(7, NI), dim3(256), 0, stream,
                       x, w16, votes);
    hipLaunchKernelGGL(routing_k, dim3(NB), dim3(RT_THREADS), 0, stream,
                       votes, x, out);
}

// Round 16
// 114.812 us; speedup vs baseline: 1.0489x; 1.0173x over previous
//
#include <hip/hip_runtime.h>
#include <hip/hip_fp16.h>
#include <math.h>

// Problem constants
#define NB 392      // n = b*oh*ow = 2*14*14
#define NI 288      // K*K*B = 9*32
#define NC 32       // C
#define NQ 16       // PSIZE
#define CQ 512      // NC*NQ
#define CH 544      // B*(PSIZE+1)
#define EPSV 1e-6f

// votes are fp8 e4m3 scaled by 32; routing descales algebraically.
#define VSCALE 32.0f
#define VINV (1.0f / 32.0f)

// out layout (floats)
#define OFF_AOUT 200704       // NB*CQ
#define OFF_CAT  213248       // OFF_AOUT + NB*NC

#define RT_THREADS 512
#define RT_WAVES 8

typedef _Float16 v4h __attribute__((ext_vector_type(4)));
typedef float v4f __attribute__((ext_vector_type(4)));
typedef float v2f __attribute__((ext_vector_type(2)));

// ---------------------------------------------------------------------------
// Gather from x via the unfold channel-major reinterpret.
__device__ __forceinline__ float gather_x(const float* __restrict__ x, int n, int j) {
    int c_idx = j / 9;
    int rem = j - c_idx * 9;
    int ki = rem / 3;
    int kj = rem - ki * 3;
    int b_ = n / 196;
    int rest = n - b_ * 196;
    int yy = rest / 14;
    int xx = rest - yy * 14;
    int iy = yy + ki - 1;
    int ix = xx + kj - 1;
    float v = 0.f;
    if ((unsigned)iy < 14u && (unsigned)ix < 14u)
        v = x[((b_ * 14 + iy) * 14 + ix) * CH + c_idx];
    return v;
}

// ---------------------------------------------------------------------------
// votes via swapped-operand mfma 16x16x16 f16, reading wts DIRECTLY
// (prep_w + w16 array + one launch eliminated).
// Block (mtt 0..6, i 0..287), 256 threads = 4 waves, M=64 rows of n.
// - A-frag: 4 p-values/lane gathered from x in-lane (block owns its n-range).
// - B-frag: lane (col,quad) needs wts[i][ct][quad*4+kk][col] -- 4 scalar
//   dword loads; each 16-lane quad-group covers a CONTIGUOUS 64 B (col spans
//   q), and wts[i] = 32 KB exactly fits L1, reused by 4 waves x 7 mtt blocks.
//   No LDS transpose (round-13's 8-way-conflict mistake avoided).
// - mfma(bv, av) puts 4 consecutive cq for one n-row in each lane;
//   cvt_pk_fp8 packs them into one u32 -> single conflict-free ds_write_b32.
// - ct-chunked staging (9 KB tile), 64 rows x 128 B contiguous stores.
__global__ __launch_bounds__(256) void votes_k(const float* __restrict__ x,
                                               const float* __restrict__ wts,
                                               uchar* __restrict__ votes) {
    __shared__ uint tile[64 * 36];      // 9 KB, pitch 36 dwords (144 B)
    int mtt = blockIdx.x;         // 0..6
    int i = blockIdx.y;           // 0..287
    int t = threadIdx.x;
    int wv = t >> 6;
    int l = t & 63;
    int col = l & 15;
    int quad = l >> 4;

    // A-side p-frag: gather 4 p-values from x in-lane (n_row = col-mapped)
    int n_row = mtt * 64 + wv * 16 + col;
    v4h av = {};
    if (n_row < NB) {
        int jb = (i >> 5) * CH + (i & 31) * 16 + quad * 4;
#pragma unroll
        for (int kk = 0; kk < 4; ++kk)
            av[kk] = (_Float16)gather_x(x, n_row, jb + kk);
    }

    const float* wb = wts + (size_t)i * 8192 + quad * 64 + col;
    const uchar* tileb = (const uchar*)tile;

    for (int ch = 0; ch < 4; ++ch) {
#pragma unroll
        for (int c8 = 0; c8 < 8; ++c8) {
            int ct = ch * 8 + c8;
            const float* wp = wb + ct * 256;
            v4h bv;
            bv[0] = (_Float16)wp[0];
            bv[1] = (_Float16)wp[16];
            bv[2] = (_Float16)wp[32];
            bv[3] = (_Float16)wp[48];
            v4f acc = {0.f, 0.f, 0.f, 0.f};
            acc = __builtin_amdgcn_mfma_f32_16x16x16f16(bv, av, acc, 0, 0, 0);
            // lane holds votes[n=...+col][cq = ct*16 + quad*4 + 0..3]
            uint u = __builtin_amdgcn_cvt_pk_fp8_f32(acc[0] * VSCALE, acc[1] * VSCALE, 0, false);
            u = __builtin_amdgcn_cvt_pk_fp8_f32(acc[2] * VSCALE, acc[3] * VSCALE, u, true);
            tile[(wv * 16 + col) * 36 + c8 * 4 + quad] = u;
        }
        __syncthreads();
        // 64 rows x 8 uint4 = 512 uint4; 2 steps; 8 lanes store a row's 128 B.
#pragma unroll
        for (int k = 0; k < 2; ++k) {
            int idx = k * 256 + t;
            int row = idx >> 3;
            int off = idx & 7;
            int n_out = mtt * 64 + row;
            if (n_out < NB) {
                uint4 d = *(const uint4*)&tileb[row * 144 + off * 16];
                *(uint4*)(votes + (((size_t)n_out * NI + i) << 9) + ch * 128 + off * 16) = d;
            }
        }
        __syncthreads();
    }
}

// ---------------------------------------------------------------------------
// Fused dynamic routing, 3 passes over fp8 votes. Block = n, 512 threads.
// Computes its own afs (288 trivial gathers). Lane: c = l&31, g = l>>5;
// wave wv step s handles i = (s*8+wv)*2+g. vjr pre-scaled x1/32 so the
// agreement dot uses raw fp8-decoded votes; s_j descaled once per column per
// iter. Scratch [q*32+c] conflict-free. Depth-4 prefetch.
__global__ __launch_bounds__(RT_THREADS) void routing_k(const uchar* __restrict__ votes,
                                                        const float* __restrict__ x,
                                                        float* __restrict__ out) {
    __shared__ float afs[NI];
    __shared__ float sred[RT_WAVES * CQ];   // 16 KB, [group][q*32+c]
    __shared__ float vj[CQ];                // [q*32+c]
    __shared__ float aout_s[NC];

    int n = blockIdx.x;
    int t = threadIdx.x;
    int wv = t >> 6;      // 0..7
    int l = t & 63;
    int c = l & 31;
    int g = l >> 5;

    if (t < NI) {
        int j = (t >> 5) * CH + 512 + (t & 31);
        float v = gather_x(x, n, j);
        float a = fminf(fmaxf(v, 1e-4f), 1.0f);
        afs[t] = a / (a + EPSV);
    }
    __syncthreads();

    const uchar* vb = votes + (size_t)n * NI * 512;
    float vjr[16];    // cumulative vj, PRE-SCALED by 1/32
    float sreg[16];

#define VROW(S) (((const uint4*)(vb + ((size_t)(((((S) << 3) + wv) << 1) + g) << 9)))[c])

    for (int iter = 0; iter < 3; ++iter) {
#pragma unroll
        for (int q = 0; q < 16; ++q) sreg[q] = 0.f;

        uint4 f0 = VROW(0), f1 = VROW(1), f2 = VROW(2), f3 = VROW(3);

#pragma clang loop unroll_count(2)
        for (int s = 0; s < 18; ++s) {
            int i = ((s << 3) + wv) * 2 + g;
            uint4 cur = f0;
            f0 = f1; f1 = f2; f2 = f3;
            if (s + 4 < 18) f3 = VROW(s + 4);

            float vt[16];   // raw fp8-decoded (x32-scaled votes)
            {
                v2f p;
                p = __builtin_amdgcn_cvt_pk_f32_fp8(cur.x, false); vt[0] = p[0];  vt[1] = p[1];
                p = __builtin_amdgcn_cvt_pk_f32_fp8(cur.x, true);  vt[2] = p[0];  vt[3] = p[1];
                p = __builtin_amdgcn_cvt_pk_f32_fp8(cur.y, false); vt[4] = p[0];  vt[5] = p[1];
                p = __builtin_amdgcn_cvt_pk_f32_fp8(cur.y, true);  vt[6] = p[0];  vt[7] = p[1];
                p = __builtin_amdgcn_cvt_pk_f32_fp8(cur.z, false); vt[8] = p[0];  vt[9] = p[1];
                p = __builtin_amdgcn_cvt_pk_f32_fp8(cur.z, true);  vt[10] = p[0]; vt[11] = p[1];
                p = __builtin_amdgcn_cvt_pk_f32_fp8(cur.w, false); vt[12] = p[0]; vt[13] = p[1];
                p = __builtin_amdgcn_cvt_pk_f32_fp8(cur.w, true);  vt[14] = p[0]; vt[15] = p[1];
            }
            float cij;
            if (iter == 0) {
                cij = afs[i] * (1.0f / 32.0f);
            } else {
                float ah = 0.f;   // vt(raw) . vjr(pre-scaled) == true dot
#pragma unroll
                for (int q = 0; q < 16; ++q) ah += vt[q] * vjr[q];
                float e = __expf(ah);
                float ssum = e;
                ssum += __shfl_xor(ssum, 1);
                ssum += __shfl_xor(ssum, 2);
                ssum += __shfl_xor(ssum, 4);
                ssum += __shfl_xor(ssum, 8);
                ssum += __shfl_xor(ssum, 16);
                cij = e * __builtin_amdgcn_rcpf(ssum) * afs[i];
            }
#pragma unroll
            for (int q = 0; q < 16; ++q) sreg[q] += cij * vt[q];
        }

        // fold g-halves, write 8 partial groups (layout [q*32+c]: bank==c)
#pragma unroll
        for (int q = 0; q < 16; ++q) sreg[q] += __shfl_xor(sreg[q], 32);
        if (g == 0) {
            float* sw = &sred[wv * CQ + c];
#pragma unroll
            for (int q = 0; q < 16; ++q) sw[q * 32] = sreg[q];
        }
        __syncthreads();
        {
            float ssum = 0.f;   // 512 threads == CQ columns
#pragma unroll
            for (int k = 0; k < RT_WAVES; ++k) ssum += sred[k * CQ + t];
            sred[t] = ssum * VINV;   // descale the x32 fp8 encoding ONCE
        }
        __syncthreads();

        // squash (threads 0..31, one c each; element (c,q) at sred[q*32+c])
        if (t < NC) {
            float s2 = 0.f;
#pragma unroll
            for (int q = 0; q < 16; ++q) {
                float s = sred[q * 32 + t];
                s2 += s * s;
            }
            float f = (s2 / (1.f + s2)) / sqrtf(s2 + EPSV);
            float vn2 = 0.f;
#pragma unroll
            for (int q = 0; q < 16; ++q) {
                float v = f * sred[q * 32 + t];
                vj[q * 32 + t] = v;
                vn2 += v * v;
            }
            if (iter == 2) {
                float ao = sqrtf(vn2 + EPSV);
                ao = fminf(fmaxf(ao, 1e-4f), 1.f - 1e-4f);
                aout_s[t] = ao;
            }
        }
        __syncthreads();
        if (iter < 2) {
#pragma unroll
            for (int q = 0; q < 16; ++q) {
                float v = vj[q * 32 + c] * VINV;   // pre-scale for the raw dot
                vjr[q] = (iter == 0) ? v : vjr[q] + v;
            }
        }
    }

    // outputs: p_out, a_out, concat(out).  canonical idx t: c=t>>4, q=t&15
    {
        float v = vj[(t & 15) * 32 + (t >> 4)];
        out[(size_t)n * CQ + t] = v;
        out[OFF_CAT + (size_t)n * 544 + t] = v;
    }
    if (t < NC) {
        float ao = aout_s[t];
        out[OFF_AOUT + n * 32 + t] = ao;
        out[OFF_CAT + (size_t)n * 544 + 512 + t] = ao;
    }
}

// ---------------------------------------------------------------------------
extern "C" void kernel_launch(void* const* d_in, const int* in_sizes, int n_in,
                              void* d_out, int out_size, void* d_ws, size_t ws_size,
                              hipStream_t stream) {
    const float* x = (const float*)d_in[0];
    const float* wts = (const float*)d_in[1];
    float* out = (float*)d_out;
    uchar* votes = (uchar*)d_ws;   // 57.8 MB fp8

    hipLaunchKernelGGL(votes_k, dim3(7, NI), dim3(256), 0, stream,
                       x, wts, votes);
    hipLaunchKernelGGL(routing_k, dim3(NB), dim3(RT_THREADS), 0, stream,
                       votes, x, out);
}